// Round 1
// baseline (33.200 us; speedup 1.0000x reference)
//
#include <hip/hip_runtime.h>
#include <hip/hip_bf16.h>

// RCNN bbox target generator: elementwise over N boxes.
// Inputs (f32 unless noted):
//   d_in[0] gt_rois  [1,N,5]  (cols 0:4 = gt box x1,y1,x2,y2)
//   d_in[1] rois     [1,N,5]  (cols 1:5 = ex box x1,y1,x2,y2)
//   d_in[2] labels   [N] int32
//   d_in[3] means [4], d_in[4] stds [4], d_in[5] inside_w [4]
// Output d_out (f32, 12N floats):
//   [0,4N)   bbox_targets        [1,N,4]
//   [4N,8N)  bbox_inside_weights [1,N,4]
//   [8N,12N) bbox_outside_weights[1,N,4]

__global__ __launch_bounds__(256) void rcnn_target_kernel(
    const float* __restrict__ gt_rois,
    const float* __restrict__ rois,
    const int*   __restrict__ labels,
    const float* __restrict__ means,
    const float* __restrict__ stds,
    const float* __restrict__ inside_w,
    float* __restrict__ out,
    int n)
{
    // Hoist the small parameter vectors into registers (broadcast loads, L1-hit).
    const float m0 = means[0], m1 = means[1], m2 = means[2], m3 = means[3];
    const float rs0 = 1.0f / stds[0], rs1 = 1.0f / stds[1];
    const float rs2 = 1.0f / stds[2], rs3 = 1.0f / stds[3];
    const float iw0 = inside_w[0], iw1 = inside_w[1];
    const float iw2 = inside_w[2], iw3 = inside_w[3];

    float4* __restrict__ out_t  = reinterpret_cast<float4*>(out);
    float4* __restrict__ out_wi = reinterpret_cast<float4*>(out + 4ull * (size_t)n);
    float4* __restrict__ out_wo = reinterpret_cast<float4*>(out + 8ull * (size_t)n);

    const int stride = gridDim.x * blockDim.x;
    for (int i = blockIdx.x * blockDim.x + threadIdx.x; i < n; i += stride) {
        const float* g = gt_rois + (size_t)i * 5;      // gt box at cols 0:4
        const float* r = rois    + (size_t)i * 5 + 1;  // ex box at cols 1:5

        const float gx1 = g[0], gy1 = g[1], gx2 = g[2], gy2 = g[3];
        const float ex1 = r[0], ey1 = r[1], ex2 = r[2], ey2 = r[3];

        const float ew  = ex2 - ex1 + 1.0f;
        const float eh  = ey2 - ey1 + 1.0f;
        const float ecx = ex1 + 0.5f * ew;
        const float ecy = ey1 + 0.5f * eh;
        const float gw  = gx2 - gx1 + 1.0f;
        const float gh  = gy2 - gy1 + 1.0f;
        const float gcx = gx1 + 0.5f * gw;
        const float gcy = gy1 + 0.5f * gh;

        const float dx = (gcx - ecx) / ew;
        const float dy = (gcy - ecy) / eh;
        const float dw = logf(gw / ew);
        const float dh = logf(gh / eh);

        const bool pos = labels[i] > 0;

        float4 t;
        t.x = pos ? (dx - m0) * rs0 : 0.0f;
        t.y = pos ? (dy - m1) * rs1 : 0.0f;
        t.z = pos ? (dw - m2) * rs2 : 0.0f;
        t.w = pos ? (dh - m3) * rs3 : 0.0f;

        float4 wi;
        wi.x = pos ? iw0 : 0.0f;
        wi.y = pos ? iw1 : 0.0f;
        wi.z = pos ? iw2 : 0.0f;
        wi.w = pos ? iw3 : 0.0f;

        float4 wo;
        wo.x = (wi.x > 0.0f) ? 1.0f : 0.0f;
        wo.y = (wi.y > 0.0f) ? 1.0f : 0.0f;
        wo.z = (wi.z > 0.0f) ? 1.0f : 0.0f;
        wo.w = (wi.w > 0.0f) ? 1.0f : 0.0f;

        out_t[i]  = t;
        out_wi[i] = wi;
        out_wo[i] = wo;
    }
}

extern "C" void kernel_launch(void* const* d_in, const int* in_sizes, int n_in,
                              void* d_out, int out_size, void* d_ws, size_t ws_size,
                              hipStream_t stream)
{
    const float* gt_rois  = (const float*)d_in[0];
    const float* rois     = (const float*)d_in[1];
    const int*   labels   = (const int*)d_in[2];
    const float* means    = (const float*)d_in[3];
    const float* stds     = (const float*)d_in[4];
    const float* inside_w = (const float*)d_in[5];
    float* out = (float*)d_out;

    const int n = in_sizes[2];  // labels has N elements

    const int block = 256;
    int grid = (n + block - 1) / block;
    if (grid > 2048) grid = 2048;  // grid-stride the rest

    rcnn_target_kernel<<<grid, block, 0, stream>>>(
        gt_rois, rois, labels, means, stds, inside_w, out, n);
}

// Round 2
// 32.674 us; speedup vs baseline: 1.0161x; 1.0161x over previous
//
#include <hip/hip_runtime.h>
#include <hip/hip_bf16.h>

// RCNN bbox target generator: elementwise over N boxes. Memory-bound.
// Traffic: 80MB record reads + 8MB labels + 96MB writes = 184MB -> ~29us floor.
//
// Strategy: block stages its 256 stride-5 records into LDS via coalesced
// float4 loads (records are 5 floats; 256 records = 320 float4s, block base
// is always 16B-aligned since 256*5*4B = 5120B). Threads then read their 8
// box fields from LDS (stride-5 across lanes -> 2 lanes/bank, conflict-free)
// and write one float4 per output stream, perfectly coalesced.
//
// Output d_out (f32, 12N floats):
//   [0,4N) bbox_targets | [4N,8N) inside_weights | [8N,12N) outside_weights

#define BLOCK 256

__global__ __launch_bounds__(BLOCK) void rcnn_target_kernel(
    const float* __restrict__ gt_rois,
    const float* __restrict__ rois,
    const int*   __restrict__ labels,
    const float* __restrict__ means,
    const float* __restrict__ stds,
    const float* __restrict__ inside_w,
    float* __restrict__ out,
    int n)
{
    __shared__ float sg[BLOCK * 5];   // 5120 B
    __shared__ float sr[BLOCK * 5];   // 5120 B

    const int base = blockIdx.x * BLOCK;
    const int rem  = min(BLOCK, n - base);       // boxes handled by this block
    const int nflt = 5 * rem;                    // floats to stage per array
    const int nvec = nflt >> 2;                  // whole float4s

    const float4* __restrict__ g4 = reinterpret_cast<const float4*>(gt_rois + (size_t)base * 5);
    const float4* __restrict__ r4 = reinterpret_cast<const float4*>(rois    + (size_t)base * 5);
    float4* __restrict__ sg4 = reinterpret_cast<float4*>(sg);
    float4* __restrict__ sr4 = reinterpret_cast<float4*>(sr);

    for (int idx = threadIdx.x; idx < nvec; idx += BLOCK) {
        sg4[idx] = g4[idx];
        sr4[idx] = r4[idx];
    }
    if (threadIdx.x == 0) {                      // scalar tail (last partial block only)
        for (int f = nvec * 4; f < nflt; ++f) {
            sg[f] = gt_rois[(size_t)base * 5 + f];
            sr[f] = rois[(size_t)base * 5 + f];
        }
    }
    __syncthreads();

    const int t = threadIdx.x;
    const int i = base + t;
    if (i >= n) return;

    // Parameter vectors: broadcast scalar loads, L1-resident.
    const float m0 = means[0], m1 = means[1], m2 = means[2], m3 = means[3];
    const float rs0 = 1.0f / stds[0], rs1 = 1.0f / stds[1];
    const float rs2 = 1.0f / stds[2], rs3 = 1.0f / stds[3];
    const float iw0 = inside_w[0], iw1 = inside_w[1];
    const float iw2 = inside_w[2], iw3 = inside_w[3];

    const float* g = sg + 5 * t;       // gt box: cols 0:4 of record
    const float* r = sr + 5 * t + 1;   // ex box: cols 1:5 of record

    const float gx1 = g[0], gy1 = g[1], gx2 = g[2], gy2 = g[3];
    const float ex1 = r[0], ey1 = r[1], ex2 = r[2], ey2 = r[3];

    const float ew  = ex2 - ex1 + 1.0f;
    const float eh  = ey2 - ey1 + 1.0f;
    const float ecx = ex1 + 0.5f * ew;
    const float ecy = ey1 + 0.5f * eh;
    const float gw  = gx2 - gx1 + 1.0f;
    const float gh  = gy2 - gy1 + 1.0f;
    const float gcx = gx1 + 0.5f * gw;
    const float gcy = gy1 + 0.5f * gh;

    const float dx = (gcx - ecx) / ew;
    const float dy = (gcy - ecy) / eh;
    const float dw = logf(gw / ew);
    const float dh = logf(gh / eh);

    const bool pos = labels[i] > 0;

    float4 tg;
    tg.x = pos ? (dx - m0) * rs0 : 0.0f;
    tg.y = pos ? (dy - m1) * rs1 : 0.0f;
    tg.z = pos ? (dw - m2) * rs2 : 0.0f;
    tg.w = pos ? (dh - m3) * rs3 : 0.0f;

    float4 wi;
    wi.x = pos ? iw0 : 0.0f;
    wi.y = pos ? iw1 : 0.0f;
    wi.z = pos ? iw2 : 0.0f;
    wi.w = pos ? iw3 : 0.0f;

    float4 wo;
    wo.x = (wi.x > 0.0f) ? 1.0f : 0.0f;
    wo.y = (wi.y > 0.0f) ? 1.0f : 0.0f;
    wo.z = (wi.z > 0.0f) ? 1.0f : 0.0f;
    wo.w = (wi.w > 0.0f) ? 1.0f : 0.0f;

    float4* __restrict__ out_t  = reinterpret_cast<float4*>(out);
    float4* __restrict__ out_wi = reinterpret_cast<float4*>(out + 4ull * (size_t)n);
    float4* __restrict__ out_wo = reinterpret_cast<float4*>(out + 8ull * (size_t)n);

    out_t[i]  = tg;
    out_wi[i] = wi;
    out_wo[i] = wo;
}

extern "C" void kernel_launch(void* const* d_in, const int* in_sizes, int n_in,
                              void* d_out, int out_size, void* d_ws, size_t ws_size,
                              hipStream_t stream)
{
    const float* gt_rois  = (const float*)d_in[0];
    const float* rois     = (const float*)d_in[1];
    const int*   labels   = (const int*)d_in[2];
    const float* means    = (const float*)d_in[3];
    const float* stds     = (const float*)d_in[4];
    const float* inside_w = (const float*)d_in[5];
    float* out = (float*)d_out;

    const int n = in_sizes[2];  // labels element count == N

    const int grid = (n + BLOCK - 1) / BLOCK;
    rcnn_target_kernel<<<grid, BLOCK, 0, stream>>>(
        gt_rois, rois, labels, means, stds, inside_w, out, n);
}